// Round 1
// baseline (1528.508 us; speedup 1.0000x reference)
//
#include <hip/hip_runtime.h>

// Problem constants (static per reference)
#define B_SZ    16
#define N_NODES 1024
#define P_TOK   256
#define D_DIM   64
#define K_ANCH  26   // ceil(256 * 0.1)

#define NC_CHUNKS 32                  // n-chunks for the streaming partial pass
#define N_CHUNK   (N_NODES / NC_CHUNKS)   // 32 n-rows per block
#define PD4       (P_TOK * D_DIM / 4)     // 4096 float4 per (b,n) plane

// ---------------------------------------------------------------------------
// K1a: partial column sums of adp [1024,1024].
// ---------------------------------------------------------------------------
__global__ __launch_bounds__(256)
void k_imp_partial(const float* __restrict__ adp, float* __restrict__ partial) {
    int j  = blockIdx.x * 256 + threadIdx.x;   // column
    int rc = blockIdx.y;                       // row chunk 0..15
    const float* src = adp + (size_t)rc * 64 * N_NODES + j;
    float s = 0.f;
    #pragma unroll 8
    for (int i = 0; i < 64; ++i)
        s += src[i * N_NODES];                 // coalesced across j
    partial[rc * N_NODES + j] = s;
}

// K1b: importance[j] = (1/1024) * sum over 16 partials
__global__ __launch_bounds__(256)
void k_imp_final(const float* __restrict__ partial, float* __restrict__ imp) {
    int j = blockIdx.x * 256 + threadIdx.x;
    float s = 0.f;
    #pragma unroll
    for (int rc = 0; rc < 16; ++rc)
        s += partial[rc * N_NODES + j];
    imp[j] = s * (1.0f / N_NODES);
}

// ---------------------------------------------------------------------------
// Pass A: STREAMING partial reduction over n.
// Old K2 read patches with 256B granules at 64KB stride (DRAM-scatter,
// ~0.86 TB/s effective). Here block (b,nc) reads 32 contiguous n-planes
// (2 MB fully sequential; every wave-load = 1KB contiguous).
//   p_mean4 [b,nc][4096] += patches plane sums  (register accumulators)
//   p_score [b,nc][256]   = sum_n ||patches[b,n,p,:]|| * imp[n]
// Thread t owns float4 slots f = t + 256k (k=0..15): d4 = t&15, p = (t>>4)+16k.
// Norm over d = 64 elems = 16 lanes x 4: shfl_xor butterfly within 16-lane group.
// VGPR ~160 (16 v + 16 macc float4 + 16 score) -> 2 waves/SIMD via launch_bounds.
// ---------------------------------------------------------------------------
__global__ __launch_bounds__(256, 2)
void k_partial_stream(const float* __restrict__ patches,
                      const float* __restrict__ imp,
                      float* __restrict__ p_score,    // [B*NC, 256]
                      float4* __restrict__ p_mean4)   // [B*NC, 4096]
{
    __shared__ float s_imp[N_CHUNK];
    int t  = threadIdx.x;
    int b  = blockIdx.x >> 5;        // / NC_CHUNKS
    int nc = blockIdx.x & 31;        // % NC_CHUNKS

    if (t < N_CHUNK) s_imp[t] = imp[nc * N_CHUNK + t];
    __syncthreads();

    const float4* base4 = (const float4*)patches
        + (size_t)(b * N_NODES + nc * N_CHUNK) * PD4;

    float4 macc[16];
    float  score[16];
    #pragma unroll
    for (int k = 0; k < 16; ++k) {
        macc[k] = make_float4(0.f, 0.f, 0.f, 0.f);
        score[k] = 0.f;
    }

    for (int n = 0; n < N_CHUNK; ++n) {
        const float4* row = base4 + (size_t)n * PD4;
        float4 v[16];
        #pragma unroll
        for (int k = 0; k < 16; ++k) v[k] = row[t + 256 * k];  // 16x 1KB/wave, contiguous
        float wn = s_imp[n];
        #pragma unroll
        for (int k = 0; k < 16; ++k) {
            float4 x = v[k];
            macc[k].x += x.x; macc[k].y += x.y; macc[k].z += x.z; macc[k].w += x.w;
            float sq = x.x*x.x + x.y*x.y + x.z*x.z + x.w*x.w;
            sq += __shfl_xor(sq, 1);
            sq += __shfl_xor(sq, 2);
            sq += __shfl_xor(sq, 4);
            sq += __shfl_xor(sq, 8);
            score[k] += sqrtf(sq) * wn;
        }
    }

    size_t outb = (size_t)(b * NC_CHUNKS + nc);
    float4* pm = p_mean4 + outb * PD4;
    #pragma unroll
    for (int k = 0; k < 16; ++k) pm[t + 256 * k] = macc[k];   // coalesced

    if ((t & 15) == 0) {                                      // one lane per p-group
        float* ps = p_score + outb * P_TOK;
        int m = t >> 4;
        #pragma unroll
        for (int k = 0; k < 16; ++k) ps[m + 16 * k] = score[k];
    }
}

// ---------------------------------------------------------------------------
// K3: fused score-reduce + top-k (exact jax.lax.top_k tie semantics: value
// desc, lower index first) + mean-reduce+gather of the 26 winning rows only.
// One 256-thread block per batch. Reads 32 KB scores + 212 KB partial means.
// ---------------------------------------------------------------------------
__global__ __launch_bounds__(P_TOK)
void k_topk_gather(const float* __restrict__ p_score,
                   const float4* __restrict__ p_mean4,
                   float4* __restrict__ anchors4) {
    __shared__ float s[P_TOK];
    __shared__ int   s_idx[K_ANCH];
    int b = blockIdx.x;
    int j = threadIdx.x;

    // reduce partial scores over nc (coalesced: consecutive j -> consecutive addr)
    float v = 0.f;
    const float* src = p_score + (size_t)b * NC_CHUNKS * P_TOK + j;
    #pragma unroll 8
    for (int nc = 0; nc < NC_CHUNKS; ++nc) v += src[nc * P_TOK];
    s[j] = v;
    __syncthreads();

    int rank = 0;
    #pragma unroll 8
    for (int i = 0; i < P_TOK; ++i) {
        float si = s[i];
        rank += (si > v) || (si == v && i < j);
    }
    if (rank < K_ANCH) s_idx[rank] = j;
    __syncthreads();

    // cooperative mean-reduce+gather of the K winning rows
    const float4* pmb = p_mean4 + (size_t)b * NC_CHUNKS * PD4;
    const float inv = 1.0f / N_NODES;
    for (int item = j; item < K_ANCH * 16; item += P_TOK) {
        int a  = item >> 4;          // anchor rank
        int d4 = item & 15;
        int p  = s_idx[a];
        const float4* ap = pmb + p * 16 + d4;
        float4 acc = make_float4(0.f, 0.f, 0.f, 0.f);
        #pragma unroll 8
        for (int nc = 0; nc < NC_CHUNKS; ++nc) {
            float4 x = ap[(size_t)nc * PD4];
            acc.x += x.x; acc.y += x.y; acc.z += x.z; acc.w += x.w;
        }
        anchors4[((size_t)b * K_ANCH + a) * 16 + d4] =
            make_float4(acc.x * inv, acc.y * inv, acc.z * inv, acc.w * inv);
    }
}

// ---------------------------------------------------------------------------
// K4: broadcast anchors [b, k*d] to out [b, n, k*d].  Pure streaming write;
// anchors (106 KB) stays L1/L2-resident.
// ---------------------------------------------------------------------------
__global__ __launch_bounds__(256)
void k_broadcast(const float4* __restrict__ anchors4,
                 float4* __restrict__ out4,
                 unsigned total4) {
    const unsigned PER_B = (unsigned)N_NODES * K_ANCH * D_DIM / 4;  // 425984
    const unsigned ROW4  = (unsigned)K_ANCH * D_DIM / 4;            // 416
    unsigned stride = gridDim.x * blockDim.x;
    for (unsigned f = blockIdx.x * blockDim.x + threadIdx.x; f < total4; f += stride) {
        unsigned b = f / PER_B;       // magic-mul division
        unsigned r = f % ROW4;        // exact: PER_B % ROW4 == 0
        out4[f] = anchors4[b * ROW4 + r];
    }
}

// ---------------------------------------------------------------------------
extern "C" void kernel_launch(void* const* d_in, const int* in_sizes, int n_in,
                              void* d_out, int out_size, void* d_ws, size_t ws_size,
                              hipStream_t stream) {
    const float* patches = (const float*)d_in[0];   // [16,1024,256,64] fp32
    const float* adp     = (const float*)d_in[1];   // [1024,1024] fp32
    float* out = (float*)d_out;                     // [16*1024, 26, 64] fp32

    // ws layout (unchanged footprint from verified kernel, <= 192512 B):
    //   imp     @ 0      (4096)
    //   partial @ 20480  (65536)   - adp column partials
    //   anchors @ 86016  (106496)
    char* ws = (char*)d_ws;
    float* imp     = (float*)(ws + 0);
    float* partial = (float*)(ws + 20480);
    float* anchors = (float*)(ws + 86016);

    // Large partials staged in d_out (fully overwritten by K4 afterwards):
    //   p_mean4 @ float 0        : 16*32*4096 float4 = 32 MiB
    //   p_score @ float 8388608  : 16*32*256 floats  = 512 KiB
    float4* p_mean4 = (float4*)out;
    float*  p_score = out + (size_t)B_SZ * NC_CHUNKS * PD4 * 4;

    k_imp_partial<<<dim3(N_NODES / 256, 16), dim3(256), 0, stream>>>(adp, partial);
    k_imp_final  <<<dim3(N_NODES / 256),     dim3(256), 0, stream>>>(partial, imp);

    // 512 blocks (2/CU), each streams 2 MB contiguously
    k_partial_stream<<<dim3(B_SZ * NC_CHUNKS), dim3(256), 0, stream>>>(
        patches, imp, p_score, p_mean4);

    k_topk_gather<<<dim3(B_SZ), dim3(P_TOK), 0, stream>>>(
        p_score, p_mean4, (float4*)anchors);

    unsigned total4 = (unsigned)out_size / 4;       // 6,815,744 float4
    k_broadcast<<<dim3(4096), dim3(256), 0, stream>>>(
        (const float4*)anchors, (float4*)out, total4);
}